// Round 1
// baseline (607.095 us; speedup 1.0000x reference)
//
#include <hip/hip_runtime.h>
#include <stdint.h>

#define B_N 16384
#define D_N 4096
#define E_N 128
#define C_N 128
#define H_N 8

typedef __attribute__((ext_vector_type(8))) short short8;
typedef __attribute__((ext_vector_type(4))) float f32x4;

__device__ __forceinline__ unsigned short f2bf(float f) {
  union { float f; unsigned u; } c; c.f = f;
  unsigned u = c.u;
  unsigned r = u + 0x7fffu + ((u >> 16) & 1u);
  return (unsigned short)(r >> 16);
}

__device__ __forceinline__ void gload_lds16(const void* g, void* l) {
  __builtin_amdgcn_global_load_lds((const __attribute__((address_space(1))) void*)g,
                                   (__attribute__((address_space(3))) void*)l,
                                   16, 0, 0);
}

// ---------------- P1: k/v tables + Wf,Wc bf16 conversion ----------------
__global__ void p1_kernel(
    const float* __restrict__ label_emb, const float* __restrict__ Wk,
    const float* __restrict__ bk, const float* __restrict__ Wv,
    const float* __restrict__ bv, const float* __restrict__ Wf,
    const float* __restrict__ Wc, float* __restrict__ k_ws,
    float* __restrict__ v_ws, unsigned short* __restrict__ Wf_bf,
    unsigned short* __restrict__ Wc_bf) {
  const int NT = gridDim.x * blockDim.x;
  const int t0 = blockIdx.x * blockDim.x + threadIdx.x;
  // k[c][o] = label_emb[c,:]·Wk[o,:] + bk[o];  v likewise
  for (int i = t0; i < C_N * E_N; i += NT) {
    const int c = i >> 7, o = i & 127;
    const float* le = label_emb + c * E_N;
    const float* wk = Wk + o * E_N;
    const float* wv = Wv + o * E_N;
    float ak = 0.f, av = 0.f;
    for (int e = 0; e < E_N; ++e) {
      const float l = le[e];
      ak += l * wk[e];
      av += l * wv[e];
    }
    k_ws[i] = ak + bk[o];
    v_ws[i] = av + bv[o];
  }
  // Wf -> bf16 (plain row-major [E][D])
  for (int i = t0; i < (E_N * D_N) / 4; i += NT) {
    const f32x4 v4 = ((const f32x4*)Wf)[i];
    unsigned lo = (unsigned)f2bf(v4[0]) | ((unsigned)f2bf(v4[1]) << 16);
    unsigned hi = (unsigned)f2bf(v4[2]) | ((unsigned)f2bf(v4[3]) << 16);
    ((uint2*)Wf_bf)[i] = make_uint2(lo, hi);
  }
  // Wc -> bf16 (plain [j][e2])
  for (int i = t0; i < C_N * E_N; i += NT) Wc_bf[i] = f2bf(Wc[i]);
}

// ---------------- P2: M = scale·Wq·K  (scores = f@M), V2T = (V·Wo)^T, bs ----------------
__global__ void p2_kernel(const float* __restrict__ Wq, const float* __restrict__ bq,
                          const float* __restrict__ Wo, const float* __restrict__ k_ws,
                          const float* __restrict__ v_ws, unsigned short* __restrict__ M_bf,
                          unsigned short* __restrict__ V2T_bf, float* __restrict__ bs_ws) {
  const int NT = gridDim.x * blockDim.x;
  const int t0 = blockIdx.x * blockDim.x + threadIdx.x;
  const float scale = 0.25f;  // 1/sqrt(16)
  // M[hc][e] = scale * sum_d Wq[h*16+d][e] * k[c][h*16+d]   (layout [1024][128])
  for (int i = t0; i < 1024 * 128; i += NT) {
    const int hc = i >> 7, e = i & 127;
    const int h = hc >> 7, c = hc & 127;
    float acc = 0.f;
    for (int d = 0; d < 16; ++d)
      acc += Wq[(h * 16 + d) * E_N + e] * k_ws[c * E_N + h * 16 + d];
    M_bf[hc * 128 + e] = f2bf(scale * acc);
  }
  // V2T[e2][hc] = sum_d v[c][h*16+d] * Wo[e2][h*16+d]   (layout [128][1024])
  for (int i = t0; i < 128 * 1024; i += NT) {
    const int e2 = i >> 10, hc = i & 1023;
    const int h = hc >> 7, c = hc & 127;
    float acc = 0.f;
    for (int d = 0; d < 16; ++d)
      acc += v_ws[c * E_N + h * 16 + d] * Wo[e2 * E_N + h * 16 + d];
    V2T_bf[e2 * 1024 + hc] = f2bf(acc);
  }
  // bs[hc] = scale * sum_d bq[h*16+d] * k[c][h*16+d]
  for (int i = t0; i < 1024; i += NT) {
    const int h = i >> 7, c = i & 127;
    float acc = 0.f;
    for (int d = 0; d < 16; ++d) acc += bq[h * 16 + d] * k_ws[c * E_N + h * 16 + d];
    bs_ws[i] = scale * acc;
  }
}

// ---------------- G: f_bf16 = bf16(x @ Wf.T + bf), pre-swizzled layout ----------------
// grid 256 blocks (64 rows each), 256 threads = 4 waves, wave-tile 16x128.
__global__ __launch_bounds__(256) void g_kernel(
    const float* __restrict__ x, const unsigned short* __restrict__ Wf_bf,
    const float* __restrict__ bfv, unsigned short* __restrict__ f_bf) {
  __shared__ unsigned short Bt[2][128 * 64];  // [buf][n*64 + k] (swizzled granules)
  const int tid = threadIdx.x;
  const int wave = tid >> 6;
  const int lane = tid & 63;
  const int l15 = lane & 15;
  const int kg = lane >> 4;
  const int blk = blockIdx.x;

  const long rowA = (long)blk * 64 + wave * 16 + l15;  // A row owned by this lane
  const float* xrow = x + rowA * D_N;

  const f32x4 zero = {0.f, 0.f, 0.f, 0.f};
  f32x4 acc[8];
#pragma unroll
  for (int i = 0; i < 8; ++i) acc[i] = zero;

  f32x4 aC[2][2], aN[2][2];

  // prologue: stage B(0) into buf0, load A(0)
#pragma unroll
  for (int it = 0; it < 4; ++it) {
    const int slot = it * 256 + tid;
    const int n = slot >> 3, ch = slot & 7;
    gload_lds16(Wf_bf + n * D_N + ((ch ^ (n & 7)) << 3), &Bt[0][slot * 8]);
  }
#pragma unroll
  for (int s = 0; s < 2; ++s) {
    const float* p = xrow + s * 32 + kg * 8;
    aC[s][0] = *(const f32x4*)p;
    aC[s][1] = *(const f32x4*)(p + 4);
    aN[s][0] = aC[s][0];
    aN[s][1] = aC[s][1];
  }
  __syncthreads();

  for (int ks = 0; ks < 64; ++ks) {
    const int buf = ks & 1;
    if (ks + 1 < 64) {
      // prefetch next B tile into other buffer + next A regs (overlap with compute)
#pragma unroll
      for (int it = 0; it < 4; ++it) {
        const int slot = it * 256 + tid;
        const int n = slot >> 3, ch = slot & 7;
        gload_lds16(Wf_bf + n * D_N + (ks + 1) * 64 + ((ch ^ (n & 7)) << 3),
                    &Bt[buf ^ 1][slot * 8]);
      }
#pragma unroll
      for (int s = 0; s < 2; ++s) {
        const float* p = xrow + (ks + 1) * 64 + s * 32 + kg * 8;
        aN[s][0] = *(const f32x4*)p;
        aN[s][1] = *(const f32x4*)(p + 4);
      }
    }
#pragma unroll
    for (int s = 0; s < 2; ++s) {
      short8 af;
#pragma unroll
      for (int j = 0; j < 4; ++j) {
        af[j] = (short)f2bf(aC[s][0][j]);
        af[4 + j] = (short)f2bf(aC[s][1][j]);
      }
#pragma unroll
      for (int fn = 0; fn < 8; ++fn) {
        const int n = fn * 16 + l15;
        const int g = s * 4 + kg;
        const short8 bq8 = *(const short8*)&Bt[buf][n * 64 + ((g ^ (n & 7)) << 3)];
        acc[fn] = __builtin_amdgcn_mfma_f32_16x16x32_bf16(af, bq8, acc[fn], 0, 0, 0);
      }
    }
    __syncthreads();
#pragma unroll
    for (int s = 0; s < 2; ++s) {
      aC[s][0] = aN[s][0];
      aC[s][1] = aN[s][1];
    }
  }

  // epilogue: f = acc + bf, store bf16 with per-row granule swizzle
  const int rbase = blk * 64 + wave * 16;
#pragma unroll
  for (int fn = 0; fn < 8; ++fn) {
    const int col = fn * 16 + l15;
    const float bias = bfv[col];
    const int gran = col >> 3;
#pragma unroll
    for (int r = 0; r < 4; ++r) {
      const int row = rbase + kg * 4 + r;
      f_bf[(long)row * 128 + ((gran ^ (row & 15)) << 3) + (col & 7)] =
          f2bf(acc[fn][r] + bias);
    }
  }
}

// ---------------- A: scores -> softmax -> o2 -> logits (fused) ----------------
// grid 256 blocks (64 rows each), 256 threads = 4 waves, wave-tile 16 rows.
__global__ __launch_bounds__(256) void a_kernel(
    const unsigned short* __restrict__ f_bf, const unsigned short* __restrict__ M_bf,
    const float* __restrict__ bs_ws, const unsigned short* __restrict__ V2T_bf,
    const float* __restrict__ bo, const unsigned short* __restrict__ Wc_bf,
    const float* __restrict__ bc, float* __restrict__ out) {
  __shared__ unsigned short fT[64 * 128];
  __shared__ unsigned short pT[64 * 128];
  __shared__ unsigned short oT[64 * 128];
  const int tid = threadIdx.x;
  const int wave = tid >> 6;
  const int lane = tid & 63;
  const int l15 = lane & 15;
  const int kg = lane >> 4;
  const int blk = blockIdx.x;

  // stage f tile (already swizzled in global) — straight 16KB copy
#pragma unroll
  for (int it = 0; it < 4; ++it) {
    const int slot = it * 256 + tid;
    gload_lds16(f_bf + (long)blk * (64 * 128) + slot * 8, &fT[slot * 8]);
  }
  __syncthreads();

  const int rl = wave * 16 + l15;  // tile-local row for A-frag reads
  const f32x4 zero = {0.f, 0.f, 0.f, 0.f};
  f32x4 o2[8];
#pragma unroll
  for (int i = 0; i < 8; ++i) o2[i] = zero;

  for (int h = 0; h < 8; ++h) {
    // scores chunk: sa = f @ M[:, h*128 : h*128+128]
    f32x4 sa[8];
#pragma unroll
    for (int i = 0; i < 8; ++i) sa[i] = zero;
#pragma unroll
    for (int s = 0; s < 4; ++s) {
      const short8 af = *(const short8*)&fT[rl * 128 + (((s * 4 + kg) ^ l15) << 3)];
#pragma unroll
      for (int fn = 0; fn < 8; ++fn) {
        const int hc = h * 128 + fn * 16 + l15;
        const short8 bq8 = *(const short8*)(M_bf + (long)hc * 128 + s * 32 + kg * 8);
        sa[fn] = __builtin_amdgcn_mfma_f32_16x16x32_bf16(af, bq8, sa[fn], 0, 0, 0);
      }
    }
    // + bs
#pragma unroll
    for (int fn = 0; fn < 8; ++fn) {
      const float b = bs_ws[h * 128 + fn * 16 + l15];
#pragma unroll
      for (int r = 0; r < 4; ++r) sa[fn][r] += b;
    }
    // softmax over the 128 cols of this head (row = kg*4+r; cols across 8 frags x 16 lanes)
    float pv[8][4];
#pragma unroll
    for (int r = 0; r < 4; ++r) {
      float m = sa[0][r];
#pragma unroll
      for (int fn = 1; fn < 8; ++fn) m = fmaxf(m, sa[fn][r]);
      m = fmaxf(m, __shfl_xor(m, 1));
      m = fmaxf(m, __shfl_xor(m, 2));
      m = fmaxf(m, __shfl_xor(m, 4));
      m = fmaxf(m, __shfl_xor(m, 8));
      float sum = 0.f;
      float ev[8];
#pragma unroll
      for (int fn = 0; fn < 8; ++fn) {
        ev[fn] = __expf(sa[fn][r] - m);
        sum += ev[fn];
      }
      sum += __shfl_xor(sum, 1);
      sum += __shfl_xor(sum, 2);
      sum += __shfl_xor(sum, 4);
      sum += __shfl_xor(sum, 8);
      const float inv = 1.f / sum;
#pragma unroll
      for (int fn = 0; fn < 8; ++fn) pv[fn][r] = ev[fn] * inv;
    }
    // attn -> LDS (bf16, swizzled)
#pragma unroll
    for (int fn = 0; fn < 8; ++fn) {
      const int col = fn * 16 + l15;
      const int gran = col >> 3;
#pragma unroll
      for (int r = 0; r < 4; ++r) {
        const int row = wave * 16 + kg * 4 + r;
        pT[row * 128 + ((gran ^ (row & 15)) << 3) + (col & 7)] = f2bf(pv[fn][r]);
      }
    }
    __syncthreads();
    // o2 += attn_h @ V2[h*128 : h*128+128, :]
#pragma unroll
    for (int s = 0; s < 4; ++s) {
      const short8 af = *(const short8*)&pT[rl * 128 + (((s * 4 + kg) ^ l15) << 3)];
#pragma unroll
      for (int fn = 0; fn < 8; ++fn) {
        const int e2 = fn * 16 + l15;
        const short8 bq8 =
            *(const short8*)(V2T_bf + (long)e2 * 1024 + h * 128 + s * 32 + kg * 8);
        o2[fn] = __builtin_amdgcn_mfma_f32_16x16x32_bf16(af, bq8, o2[fn], 0, 0, 0);
      }
    }
    __syncthreads();
  }

  // o2 + bo -> LDS bf16 (swizzled)
#pragma unroll
  for (int fn = 0; fn < 8; ++fn) {
    const int col = fn * 16 + l15;
    const float b = bo[col];
    const int gran = col >> 3;
#pragma unroll
    for (int r = 0; r < 4; ++r) {
      const int row = wave * 16 + kg * 4 + r;
      oT[row * 128 + ((gran ^ (row & 15)) << 3) + (col & 7)] = f2bf(o2[fn][r] + b);
    }
  }
  __syncthreads();

  // logits = o2 @ Wc.T + bc
  f32x4 la[8];
#pragma unroll
  for (int i = 0; i < 8; ++i) la[i] = zero;
#pragma unroll
  for (int s = 0; s < 4; ++s) {
    const short8 af = *(const short8*)&oT[rl * 128 + (((s * 4 + kg) ^ l15) << 3)];
#pragma unroll
    for (int fn = 0; fn < 8; ++fn) {
      const short8 bq8 = *(const short8*)(Wc_bf + (fn * 16 + l15) * 128 + s * 32 + kg * 8);
      la[fn] = __builtin_amdgcn_mfma_f32_16x16x32_bf16(af, bq8, la[fn], 0, 0, 0);
    }
  }
#pragma unroll
  for (int fn = 0; fn < 8; ++fn) {
    const int col = fn * 16 + l15;
    const float b = bc[col];
#pragma unroll
    for (int r = 0; r < 4; ++r) {
      const long row = (long)blk * 64 + wave * 16 + kg * 4 + r;
      out[row * 128 + col] = la[fn][r] + b;
    }
  }
}

extern "C" void kernel_launch(void* const* d_in, const int* in_sizes, int n_in,
                              void* d_out, int out_size, void* d_ws, size_t ws_size,
                              hipStream_t stream) {
  (void)in_sizes; (void)n_in; (void)out_size; (void)ws_size;
  const float* x   = (const float*)d_in[0];
  const float* le  = (const float*)d_in[1];
  const float* Wf  = (const float*)d_in[2];
  const float* bf  = (const float*)d_in[3];
  const float* Wq  = (const float*)d_in[4];
  const float* bq  = (const float*)d_in[5];
  const float* Wk  = (const float*)d_in[6];
  const float* bk  = (const float*)d_in[7];
  const float* Wv  = (const float*)d_in[8];
  const float* bv  = (const float*)d_in[9];
  const float* Wo  = (const float*)d_in[10];
  const float* bo  = (const float*)d_in[11];
  const float* Wc  = (const float*)d_in[12];
  const float* bc  = (const float*)d_in[13];
  float* out = (float*)d_out;

  char* ws = (char*)d_ws;
  unsigned short* Wf_bf  = (unsigned short*)(ws + 0);        // 1,048,576 B
  unsigned short* f_bf   = (unsigned short*)(ws + 1048576);  // 4,194,304 B
  unsigned short* M_bf   = (unsigned short*)(ws + 5242880);  //   262,144 B
  unsigned short* V2T_bf = (unsigned short*)(ws + 5505024);  //   262,144 B
  unsigned short* Wc_bf  = (unsigned short*)(ws + 5767168);  //    32,768 B
  float* k_ws            = (float*)(ws + 5799936);           //    65,536 B
  float* v_ws            = (float*)(ws + 5865472);           //    65,536 B
  float* bs_ws           = (float*)(ws + 5931008);           //     4,096 B

  hipLaunchKernelGGL(p1_kernel, dim3(256), dim3(256), 0, stream,
                     le, Wk, bk, Wv, bv, Wf, Wc, k_ws, v_ws, Wf_bf, Wc_bf);
  hipLaunchKernelGGL(p2_kernel, dim3(256), dim3(256), 0, stream,
                     Wq, bq, Wo, k_ws, v_ws, M_bf, V2T_bf, bs_ws);
  hipLaunchKernelGGL(g_kernel, dim3(B_N / 64), dim3(256), 0, stream,
                     x, Wf_bf, bf, f_bf);
  hipLaunchKernelGGL(a_kernel, dim3(B_N / 64), dim3(256), 0, stream,
                     f_bf, M_bf, bs_ws, V2T_bf, bo, Wc_bf, bc, out);
}

// Round 2
// 538.927 us; speedup vs baseline: 1.1265x; 1.1265x over previous
//
#include <hip/hip_runtime.h>
#include <stdint.h>

typedef __attribute__((ext_vector_type(8))) short short8;
typedef __attribute__((ext_vector_type(4))) float f32x4;

__device__ __forceinline__ unsigned f2bf(float f) {
  union { float f; unsigned u; } c; c.f = f;
  unsigned u = c.u;
  return (u + 0x7fffu + ((u >> 16) & 1u)) >> 16;
}

__device__ __forceinline__ void gload_lds16(const void* g, void* l) {
  __builtin_amdgcn_global_load_lds((const __attribute__((address_space(1))) void*)g,
                                   (__attribute__((address_space(3))) void*)l,
                                   16, 0, 0);
}

// stage a 32KB tile (128 rows x 128 shorts, row stride = stride shorts) into LDS,
// source-side granule swizzle (ch ^ (n&15)) so swizzled ds_read_b128 is conflict-free.
// Issued cooperatively by 256 threads (hgtid 0..255), 8 gload rounds.
__device__ __forceinline__ void stage32k(const unsigned short* __restrict__ src,
                                         int stride, unsigned short* dst, int hgtid) {
#pragma unroll
  for (int it = 0; it < 8; ++it) {
    const int slot = it * 256 + hgtid;
    const int n = slot >> 4, ch = slot & 15;
    gload_lds16(src + n * stride + ((ch ^ (n & 15)) << 3), dst + slot * 8);
  }
}

// ---------------- P: prep (k/v -> M, V2T, bs; Wf,Wc -> bf16) ----------------
// grid 73 blocks: 0..7 head-blocks, 8..71 Wf convert, 72 Wc convert.
__global__ __launch_bounds__(256) void p_kernel(
    const float* __restrict__ label_emb, const float* __restrict__ Wk,
    const float* __restrict__ bk, const float* __restrict__ Wv,
    const float* __restrict__ bv, const float* __restrict__ Wq,
    const float* __restrict__ bq, const float* __restrict__ Wo,
    const float* __restrict__ Wf, const float* __restrict__ Wc,
    unsigned short* __restrict__ M_bf, unsigned short* __restrict__ V2T_bf,
    unsigned short* __restrict__ Wc_bf, unsigned short* __restrict__ Wf_bf,
    float* __restrict__ bs_ws) {
  __shared__ float leS[128 * 128];           // 64 KB
  __shared__ float KhS[128 * 16];            // 8 KB  [c][d]
  __shared__ float VhS[128 * 16];            // 8 KB  [c][d]
  const int blk = blockIdx.x;
  const int tid = threadIdx.x;

  if (blk < 8) {
    const int h16 = blk * 16;
    for (int i = tid; i < 4096; i += 256)
      ((f32x4*)leS)[i] = ((const f32x4*)label_emb)[i];
    __syncthreads();
    // K_h, V_h (fp32)
    for (int o = tid; o < 2048; o += 256) {
      const int c = o >> 4, d = o & 15;
      const float* lrow = leS + c * 128;
      const float* wkr = Wk + (h16 + d) * 128;
      const float* wvr = Wv + (h16 + d) * 128;
      float ak = 0.f, av = 0.f;
      for (int e = 0; e < 128; ++e) {
        const float l = lrow[e];
        ak += l * wkr[e];
        av += l * wvr[e];
      }
      KhS[o] = ak + bk[h16 + d];
      VhS[o] = av + bv[h16 + d];
    }
    __syncthreads();
    // M_h[c][e] = 0.25 * sum_d Wq[h16+d][e] * K_h[c][d]
    for (int o = tid; o < 16384; o += 256) {
      const int c = o >> 7, e = o & 127;
      const float* kc = KhS + c * 16;
      float acc = 0.f;
#pragma unroll
      for (int d = 0; d < 16; ++d) acc += Wq[(h16 + d) * 128 + e] * kc[d];
      M_bf[(blk * 128 + c) * 128 + e] = (unsigned short)f2bf(0.25f * acc);
    }
    // V2T[e2][h*128+c] = sum_d Wo[e2][h16+d] * V_h[c][d]
    for (int o = tid; o < 16384; o += 256) {
      const int e2 = o >> 7, c = o & 127;
      const float* vc = VhS + c * 16;
      float acc = 0.f;
#pragma unroll
      for (int d = 0; d < 16; ++d) acc += Wo[e2 * 128 + h16 + d] * vc[d];
      V2T_bf[e2 * 1024 + blk * 128 + c] = (unsigned short)f2bf(acc);
    }
    // bs[h*128+c] = 0.25 * sum_d bq[h16+d] * K_h[c][d]
    for (int c = tid; c < 128; c += 256) {
      const float* kc = KhS + c * 16;
      float acc = 0.f;
#pragma unroll
      for (int d = 0; d < 16; ++d) acc += bq[h16 + d] * kc[d];
      bs_ws[blk * 128 + c] = 0.25f * acc;
    }
  } else if (blk < 72) {
    const int base = (blk - 8) * 2048;
#pragma unroll
    for (int i = 0; i < 8; ++i) {
      const int idx = base + i * 256 + tid;
      const f32x4 v4 = ((const f32x4*)Wf)[idx];
      const unsigned lo = f2bf(v4[0]) | (f2bf(v4[1]) << 16);
      const unsigned hi = f2bf(v4[2]) | (f2bf(v4[3]) << 16);
      ((uint2*)Wf_bf)[idx] = make_uint2(lo, hi);
    }
  } else {
    for (int i = tid; i < 4096; i += 256) {
      const f32x4 v4 = ((const f32x4*)Wc)[i];
      const unsigned lo = f2bf(v4[0]) | (f2bf(v4[1]) << 16);
      const unsigned hi = f2bf(v4[2]) | (f2bf(v4[3]) << 16);
      ((uint2*)Wc_bf)[i] = make_uint2(lo, hi);
    }
  }
}

// ---------------- G: f_bf = bf16swz(x @ Wf.T + bf) ----------------
// grid 256 blocks (64 rows), 512 threads = 8 waves (4 row-groups x 2 col-groups).
__global__ __launch_bounds__(512) void g_kernel(
    const float* __restrict__ x, const unsigned short* __restrict__ Wf_bf,
    const float* __restrict__ bfv, unsigned short* __restrict__ f_bf) {
  __shared__ unsigned short Bt[2][8192];  // [buf][n*64 + swizzled granules], 16 KB each
  const int tid = threadIdx.x;
  const int wave = tid >> 6, lane = tid & 63;
  const int l15 = lane & 15, kg = lane >> 4;
  const int r = wave & 3, cg = wave >> 2;
  const int blk = blockIdx.x;
  const long rowA = (long)blk * 64 + r * 16 + l15;
  const float* xrow = x + rowA * 4096;

  const f32x4 zero = {0.f, 0.f, 0.f, 0.f};
  f32x4 acc[4];
#pragma unroll
  for (int i = 0; i < 4; ++i) acc[i] = zero;
  f32x4 aC[2][2], aN[2][2];

  // prologue: stage B(0), load A(0)
#pragma unroll
  for (int it = 0; it < 2; ++it) {
    const int slot = it * 512 + tid;
    const int n = slot >> 3, ch = slot & 7;
    gload_lds16(Wf_bf + n * 4096 + ((ch ^ (n & 7)) << 3), &Bt[0][slot * 8]);
  }
#pragma unroll
  for (int s = 0; s < 2; ++s) {
    const float* p = xrow + s * 32 + kg * 8;
    aC[s][0] = *(const f32x4*)p;
    aC[s][1] = *(const f32x4*)(p + 4);
  }
  __syncthreads();

  for (int ks = 0; ks < 64; ++ks) {
    const int buf = ks & 1;
    if (ks < 63) {
      const int k0 = (ks + 1) * 64;
#pragma unroll
      for (int it = 0; it < 2; ++it) {
        const int slot = it * 512 + tid;
        const int n = slot >> 3, ch = slot & 7;
        gload_lds16(Wf_bf + n * 4096 + k0 + ((ch ^ (n & 7)) << 3),
                    &Bt[buf ^ 1][slot * 8]);
      }
#pragma unroll
      for (int s = 0; s < 2; ++s) {
        const float* p = xrow + k0 + s * 32 + kg * 8;
        aN[s][0] = *(const f32x4*)p;
        aN[s][1] = *(const f32x4*)(p + 4);
      }
    }
#pragma unroll
    for (int s = 0; s < 2; ++s) {
      short8 af;
#pragma unroll
      for (int q = 0; q < 4; ++q) {
        af[q] = (short)f2bf(aC[s][0][q]);
        af[4 + q] = (short)f2bf(aC[s][1][q]);
      }
#pragma unroll
      for (int fn = 0; fn < 4; ++fn) {
        const int n = cg * 64 + fn * 16 + l15;
        const int g = s * 4 + kg;
        const short8 b8 = *(const short8*)&Bt[buf][n * 64 + ((g ^ (n & 7)) << 3)];
        acc[fn] = __builtin_amdgcn_mfma_f32_16x16x32_bf16(af, b8, acc[fn], 0, 0, 0);
      }
    }
    __syncthreads();
    if (ks < 63) {
#pragma unroll
      for (int s = 0; s < 2; ++s) {
        aC[s][0] = aN[s][0];
        aC[s][1] = aN[s][1];
      }
    }
  }

  // epilogue: bias + bf16 + granule swizzle (^ row&15) for A-frag reads downstream
#pragma unroll
  for (int fn = 0; fn < 4; ++fn) {
    const int col = cg * 64 + fn * 16 + l15;
    const float bias = bfv[col];
    const int gran = col >> 3;
#pragma unroll
    for (int rr = 0; rr < 4; ++rr) {
      const int rowloc = r * 16 + kg * 4 + rr;
      const long grow = (long)blk * 64 + rowloc;
      f_bf[grow * 128 + ((gran ^ (rowloc & 15)) << 3) + (col & 7)] =
          (unsigned short)f2bf(acc[fn][rr] + bias);
    }
  }
}

// ---------------- A: scores -> softmax -> o2 -> logits (fused, LDS-staged B) ----------------
// grid 256 blocks (64 rows), 512 threads = 8 waves: 4 row-groups x 2 head-groups (j=0: h0-3, j=1: h4-7).
__global__ __launch_bounds__(512) void a_kernel(
    const unsigned short* __restrict__ f_bf, const unsigned short* __restrict__ M_bf,
    const float* __restrict__ bs_ws, const unsigned short* __restrict__ V2T_bf,
    const float* __restrict__ bo, const unsigned short* __restrict__ Wc_bf,
    const float* __restrict__ bc, float* __restrict__ out) {
  __shared__ unsigned short stg[2][16384];  // per head-group 32 KB stage (M_h / V2_h / Wc time-shared)
  __shared__ unsigned short pT[2][8192];    // per head-group 16 KB attn transpose
  const int tid = threadIdx.x;
  const int wave = tid >> 6, lane = tid & 63;
  const int l15 = lane & 15, kg = lane >> 4;
  const int r = wave & 3, j = wave >> 2;
  const int hgtid = tid & 255;
  const int blk = blockIdx.x;
  const int rl = r * 16 + l15;
  const long grow = (long)blk * 64 + rl;

  // f A-fragments: one-time global load from swizzled f_bf (held in regs for all heads)
  short8 fa[4];
#pragma unroll
  for (int s = 0; s < 4; ++s)
    fa[s] = *(const short8*)(f_bf + grow * 128 + (((s * 4 + kg) ^ (rl & 15)) << 3));

  const f32x4 zero = {0.f, 0.f, 0.f, 0.f};
  f32x4 o2[8];
#pragma unroll
  for (int i = 0; i < 8; ++i) o2[i] = zero;

  unsigned short* stj = stg[j];
  stage32k(M_bf + (j * 4) * 128 * 128, 128, stj, hgtid);
  __syncthreads();

  for (int hh = 0; hh < 4; ++hh) {
    const int h = j * 4 + hh;
    // QK: sa = f @ M_h^T   (B from LDS)
    f32x4 sa[8];
#pragma unroll
    for (int i = 0; i < 8; ++i) sa[i] = zero;
#pragma unroll
    for (int s = 0; s < 4; ++s) {
#pragma unroll
      for (int fn = 0; fn < 8; ++fn) {
        const int n = fn * 16 + l15;
        const short8 b8 = *(const short8*)&stj[n * 128 + (((s * 4 + kg) ^ (n & 15)) << 3)];
        sa[fn] = __builtin_amdgcn_mfma_f32_16x16x32_bf16(fa[s], b8, sa[fn], 0, 0, 0);
      }
    }
    asm volatile("s_waitcnt lgkmcnt(0)" ::: "memory");
    // prefetch V2_h over M_h (hidden under softmax)
    stage32k(V2T_bf + h * 128, 1024, stj, hgtid);

    // + bs, softmax over 128 cols (fn frags x l15 lanes)
#pragma unroll
    for (int fn = 0; fn < 8; ++fn) {
      const float b = bs_ws[h * 128 + fn * 16 + l15];
#pragma unroll
      for (int rr = 0; rr < 4; ++rr) sa[fn][rr] += b;
    }
    float pv[8][4];
#pragma unroll
    for (int rr = 0; rr < 4; ++rr) {
      float m = sa[0][rr];
#pragma unroll
      for (int fn = 1; fn < 8; ++fn) m = fmaxf(m, sa[fn][rr]);
      m = fmaxf(m, __shfl_xor(m, 1));
      m = fmaxf(m, __shfl_xor(m, 2));
      m = fmaxf(m, __shfl_xor(m, 4));
      m = fmaxf(m, __shfl_xor(m, 8));
      float sum = 0.f;
      float ev[8];
#pragma unroll
      for (int fn = 0; fn < 8; ++fn) {
        ev[fn] = __expf(sa[fn][rr] - m);
        sum += ev[fn];
      }
      sum += __shfl_xor(sum, 1);
      sum += __shfl_xor(sum, 2);
      sum += __shfl_xor(sum, 4);
      sum += __shfl_xor(sum, 8);
      const float inv = 1.f / sum;
#pragma unroll
      for (int fn = 0; fn < 8; ++fn) pv[fn][rr] = ev[fn] * inv;
    }
    // attn -> pT (bf16, swizzled), then A-frags back (own rows, no barrier)
#pragma unroll
    for (int fn = 0; fn < 8; ++fn) {
      const int col = fn * 16 + l15;
      const int gran = col >> 3;
#pragma unroll
      for (int rr = 0; rr < 4; ++rr) {
        const int rowloc = r * 16 + kg * 4 + rr;
        pT[j][rowloc * 128 + ((gran ^ (rowloc & 15)) << 3) + (col & 7)] =
            (unsigned short)f2bf(pv[fn][rr]);
      }
    }
    short8 pa[4];
#pragma unroll
    for (int s = 0; s < 4; ++s)
      pa[s] = *(const short8*)&pT[j][rl * 128 + (((s * 4 + kg) ^ (rl & 15)) << 3)];
    __syncthreads();  // V2_h staged + hg sync

    // PV: o2 += attn_h @ V2_h
#pragma unroll
    for (int s = 0; s < 4; ++s) {
#pragma unroll
      for (int fn = 0; fn < 8; ++fn) {
        const int n = fn * 16 + l15;
        const short8 b8 = *(const short8*)&stj[n * 128 + (((s * 4 + kg) ^ (n & 15)) << 3)];
        o2[fn] = __builtin_amdgcn_mfma_f32_16x16x32_bf16(pa[s], b8, o2[fn], 0, 0, 0);
      }
    }
    asm volatile("s_waitcnt lgkmcnt(0)" ::: "memory");
    if (hh < 3) {
      stage32k(M_bf + (h + 1) * 128 * 128, 128, stj, hgtid);
    } else if (j == 0) {
      stage32k(Wc_bf, 128, stg[0], hgtid);
    }
    __syncthreads();  // next M (or Wc) staged
  }

  // cross-head-group o2 reduction (fp32 via stg[1], now dead)
  if (j == 1) {
    float* o2x = (float*)stg[1];
#pragma unroll
    for (int fn = 0; fn < 8; ++fn) {
      const int col = fn * 16 + l15;
#pragma unroll
      for (int rr = 0; rr < 4; ++rr)
        o2x[(r * 16 + kg * 4 + rr) * 128 + col] = o2[fn][rr];
    }
  }
  __syncthreads();
  if (j == 0) {
    const float* o2x = (const float*)stg[1];
    // combine + bo -> bf16 -> oT (reuse pT[0])
#pragma unroll
    for (int fn = 0; fn < 8; ++fn) {
      const int col = fn * 16 + l15;
      const float bov = bo[col];
      const int gran = col >> 3;
#pragma unroll
      for (int rr = 0; rr < 4; ++rr) {
        const int rowloc = r * 16 + kg * 4 + rr;
        const float v = o2[fn][rr] + o2x[rowloc * 128 + col] + bov;
        pT[0][rowloc * 128 + ((gran ^ (rowloc & 15)) << 3) + (col & 7)] =
            (unsigned short)f2bf(v);
      }
    }
    short8 oa[4];
#pragma unroll
    for (int s = 0; s < 4; ++s)
      oa[s] = *(const short8*)&pT[0][rl * 128 + (((s * 4 + kg) ^ (rl & 15)) << 3)];
    // logits = o2 @ Wc.T + bc   (Wc staged in stg[0])
    f32x4 la[8];
#pragma unroll
    for (int i = 0; i < 8; ++i) la[i] = zero;
#pragma unroll
    for (int s = 0; s < 4; ++s) {
#pragma unroll
      for (int fn = 0; fn < 8; ++fn) {
        const int n = fn * 16 + l15;
        const short8 b8 = *(const short8*)&stg[0][n * 128 + (((s * 4 + kg) ^ (n & 15)) << 3)];
        la[fn] = __builtin_amdgcn_mfma_f32_16x16x32_bf16(oa[s], b8, la[fn], 0, 0, 0);
      }
    }
#pragma unroll
    for (int fn = 0; fn < 8; ++fn) {
      const int col = fn * 16 + l15;
      const float bcv = bc[col];
#pragma unroll
      for (int rr = 0; rr < 4; ++rr) {
        const int rowloc = r * 16 + kg * 4 + rr;
        out[((long)blk * 64 + rowloc) * 128 + col] = la[fn][rr] + bcv;
      }
    }
  }
}

extern "C" void kernel_launch(void* const* d_in, const int* in_sizes, int n_in,
                              void* d_out, int out_size, void* d_ws, size_t ws_size,
                              hipStream_t stream) {
  (void)in_sizes; (void)n_in; (void)out_size; (void)ws_size;
  const float* x   = (const float*)d_in[0];
  const float* le  = (const float*)d_in[1];
  const float* Wf  = (const float*)d_in[2];
  const float* bf  = (const float*)d_in[3];
  const float* Wq  = (const float*)d_in[4];
  const float* bq  = (const float*)d_in[5];
  const float* Wk  = (const float*)d_in[6];
  const float* bk  = (const float*)d_in[7];
  const float* Wv  = (const float*)d_in[8];
  const float* bv  = (const float*)d_in[9];
  const float* Wo  = (const float*)d_in[10];
  const float* bo  = (const float*)d_in[11];
  const float* Wc  = (const float*)d_in[12];
  const float* bc  = (const float*)d_in[13];
  float* out = (float*)d_out;

  char* ws = (char*)d_ws;
  unsigned short* Wf_bf  = (unsigned short*)(ws + 0);        // 1,048,576 B
  unsigned short* f_bf   = (unsigned short*)(ws + 1048576);  // 4,194,304 B
  unsigned short* M_bf   = (unsigned short*)(ws + 5242880);  //   262,144 B
  unsigned short* V2T_bf = (unsigned short*)(ws + 5505024);  //   262,144 B
  unsigned short* Wc_bf  = (unsigned short*)(ws + 5767168);  //    32,768 B
  float* bs_ws           = (float*)(ws + 5799936);           //     4,096 B

  hipLaunchKernelGGL(p_kernel, dim3(73), dim3(256), 0, stream,
                     le, Wk, bk, Wv, bv, Wq, bq, Wo, Wf, Wc,
                     M_bf, V2T_bf, Wc_bf, Wf_bf, bs_ws);
  hipLaunchKernelGGL(g_kernel, dim3(256), dim3(512), 0, stream,
                     x, Wf_bf, bf, f_bf);
  hipLaunchKernelGGL(a_kernel, dim3(256), dim3(512), 0, stream,
                     f_bf, M_bf, bs_ws, V2T_bf, bo, Wc_bf, bc, out);
}